// Round 3
// baseline (67.590 us; speedup 1.0000x reference)
//
#include <hip/hip_runtime.h>
#include <math.h>

#define SD 16512            // 128 + 128*128
#define NCH 86              // split-K chunks for big GEMM
#define KCH 192             // 86*192 = 16512
#define CHUNK 65536         // per-chunk partial elements (256*256)
#define LN_EPS 1e-5f

typedef __attribute__((ext_vector_type(4))) float f32x4;
typedef __attribute__((ext_vector_type(8))) short bf16x8;

__device__ __forceinline__ unsigned bfpack(float lo, float hi) {
    unsigned a = __builtin_bit_cast(unsigned, lo);
    unsigned b = __builtin_bit_cast(unsigned, hi);
    a = (a + 0x7FFFu + ((a >> 16) & 1u)) >> 16;
    b = (b + 0x7FFFu + ((b >> 16) & 1u)) >> 16;
    return a | (b << 16);
}
__device__ __forceinline__ unsigned short bf1(float x) {
    unsigned a = __builtin_bit_cast(unsigned, x);
    return (unsigned short)((a + 0x7FFFu + ((a >> 16) & 1u)) >> 16);
}

// ---------------------------------------------------------------------------
// K1: signature via MFMA. grid 257: blocks 0..255 = batch; block 256 = Wd prep.
// sig[b] = [S1(128) | S2(128x128 row-major)] bf16.
// S2 = Ut(128 x 64k) @ DXt^T ... C[i][j] = sum_t Ut[i][t]*DXt[j][t], t=63 zero-pad.
// Also writes xbf[b][t][d] = bf16(tk[t]*x[b][t][d]) and (block 256) WdTg[d][k].
// ---------------------------------------------------------------------------
__global__ __launch_bounds__(256) void k_sig(const float* __restrict__ x,
                                             const float* __restrict__ tk,
                                             const float* __restrict__ Wd,
                                             unsigned short* __restrict__ sig,
                                             unsigned short* __restrict__ xbf,
                                             unsigned short* __restrict__ WdTg) {
    __shared__ unsigned short Ut[128][72];    // [i][t], stride 72 (144 B, 16-aligned)
    __shared__ unsigned short DXt[128][72];   // [j][t]
    __shared__ float tks[64];
    int tid = threadIdx.x;
    int b = blockIdx.x;

    if (b == 256) {
        // WdTg[d][k] = bf16(Wd[k][d]); coalesced reads, scattered small writes (L2).
        int d = tid & 127, kh = tid >> 7;
        unsigned* dst = (unsigned*)WdTg;
        for (int kk = 0; kk < 64; kk += 2) {
            int k = kh * 64 + kk;
            float v0 = Wd[(size_t)k * 128 + d];
            float v1 = Wd[(size_t)(k + 1) * 128 + d];
            dst[d * 64 + ((kh * 64 + kk) >> 1)] = bfpack(v0, v1);
        }
        return;
    }

    if (tid < 64) tks[tid] = tk[tid];
    __syncthreads();

    const float* xb = x + (size_t)b * 8192;
    unsigned short* xbb = xbf + (size_t)b * 8192;
    int i = tid & 127, th = tid >> 7;

    float x0 = tks[0] * xb[i];
    float xa = tks[th * 32] * xb[(size_t)(th * 32) * 128 + i];
    for (int tp = 0; tp < 16; ++tp) {
        int p = th * 16 + tp;
        int t0 = 2 * p;
        float xv = tks[t0 + 1] * xb[(size_t)(t0 + 1) * 128 + i];
        float dx0 = xv - xa, u0 = 0.5f * (xa + xv) - x0;
        float dx1, u1, xc;
        if (p == 31) { dx1 = 0.f; u1 = 0.f; xc = 0.f; }
        else {
            xc = tks[t0 + 2] * xb[(size_t)(t0 + 2) * 128 + i];
            dx1 = xc - xv; u1 = 0.5f * (xv + xc) - x0;
        }
        *(unsigned*)&Ut[i][t0]  = bfpack(u0, u1);
        *(unsigned*)&DXt[i][t0] = bfpack(dx0, dx1);
        xbb[(size_t)t0 * 128 + i]       = bf1(xa);
        xbb[(size_t)(t0 + 1) * 128 + i] = bf1(xv);
        if (p == 31) sig[(size_t)b * SD + i] = bf1(xv - x0);   // S1
        xa = xc;
    }
    __syncthreads();

    int w = tid >> 6, lane = tid & 63;
    int wm = w >> 1, wn = w & 1;
    int l15 = lane & 15, lg = lane >> 4;
    f32x4 acc[4][4];
    #pragma unroll
    for (int m = 0; m < 4; ++m)
        #pragma unroll
        for (int n = 0; n < 4; ++n) acc[m][n] = (f32x4){0.f, 0.f, 0.f, 0.f};

    #pragma unroll
    for (int ks = 0; ks < 2; ++ks) {
        bf16x8 af[4], bfv[4];
        #pragma unroll
        for (int m = 0; m < 4; ++m)
            af[m] = *(const bf16x8*)&Ut[wm * 64 + m * 16 + l15][ks * 32 + lg * 8];
        #pragma unroll
        for (int n = 0; n < 4; ++n)
            bfv[n] = *(const bf16x8*)&DXt[wn * 64 + n * 16 + l15][ks * 32 + lg * 8];
        #pragma unroll
        for (int m = 0; m < 4; ++m)
            #pragma unroll
            for (int n = 0; n < 4; ++n)
                acc[m][n] = __builtin_amdgcn_mfma_f32_16x16x32_bf16(af[m], bfv[n], acc[m][n], 0, 0, 0);
    }

    unsigned short* sp = sig + (size_t)b * SD + 128;
    #pragma unroll
    for (int m = 0; m < 4; ++m)
        #pragma unroll
        for (int n = 0; n < 4; ++n)
            #pragma unroll
            for (int rr = 0; rr < 4; ++rr)
                sp[(size_t)(wm * 64 + m * 16 + lg * 4 + rr) * 128 + wn * 64 + n * 16 + l15]
                    = bf1(acc[m][n][rr]);
}

// ---------------------------------------------------------------------------
// K2: bf16 MFMA split-K GEMM, BM=256 (full batch, W read ONCE), BN=128 (nt
// selects W2/Ws). grid 172 = NCH*2, 512 thr = 8 waves (4M x 2N), 64x64 wave
// tiles, 16x16x32 MFMA 4x4 frags. partial[ch][256][256].
// ---------------------------------------------------------------------------
__global__ __launch_bounds__(512) void k_gemm(const unsigned short* __restrict__ sig,
                                              const float* __restrict__ W2,
                                              const float* __restrict__ Ws,
                                              float* __restrict__ partial) {
    __shared__ unsigned short As[2][256][40];   // [row][k] pad 40
    __shared__ unsigned short Bs[2][128][40];   // [col][k] (W^T, k-contig)

    // bijective XCD swizzle (nwg=172): nt pair of a chunk lands on same XCD
    int p = blockIdx.x;
    const int q = (NCH * 2) >> 3;       // 21
    const int r = (NCH * 2) & 7;        // 4
    int xc = p & 7, o = p >> 3;
    int lid = (xc < r ? xc * (q + 1) : r * (q + 1) + (xc - r) * q) + o;
    int ch = lid >> 1;
    int nt = lid & 1;
    const float* W = nt ? Ws : W2;

    int tid = threadIdx.x;
    int w = tid >> 6, lane = tid & 63;
    int wr = w >> 1, wc = w & 1;
    int l15 = lane & 15, lg = lane >> 4;
    int k0 = ch * KCH;

    // A staging: 256 rows x 32 k bf16 = 1024 chunks of 8; 2 per thread
    int arow[2], akq[2];
    #pragma unroll
    for (int ii = 0; ii < 2; ++ii) {
        int idx = ii * 512 + tid;
        arow[ii] = idx >> 2; akq[ii] = (idx & 3) * 8;
    }
    // B staging: k-pair kp = tid&15 (32 k), col group c4 = (tid>>4)*4 (128 cols)
    int kp = tid & 15;
    int c4 = (tid >> 4) * 4;

    f32x4 acc[4][4];
    #pragma unroll
    for (int m = 0; m < 4; ++m)
        #pragma unroll
        for (int n = 0; n < 4; ++n) acc[m][n] = (f32x4){0.f, 0.f, 0.f, 0.f};

    uint4 aR[2];
    f32x4 bR0, bR1;

#define LOADG(ks)                                                                  \
    {                                                                              \
        int kb = k0 + (ks) * 32;                                                   \
        _Pragma("unroll")                                                          \
        for (int ii = 0; ii < 2; ++ii)                                             \
            aR[ii] = *(const uint4*)(sig + (size_t)arow[ii] * SD + kb + akq[ii]);  \
        const float* wp = W + (size_t)(kb + 2 * kp) * 128 + c4;                    \
        bR0 = *(const f32x4*)wp;                                                   \
        bR1 = *(const f32x4*)(wp + 128);                                           \
    }

#define WRITELDS(buf)                                                              \
    {                                                                              \
        _Pragma("unroll")                                                          \
        for (int ii = 0; ii < 2; ++ii)                                             \
            *(uint4*)&As[buf][arow[ii]][akq[ii]] = aR[ii];                         \
        _Pragma("unroll")                                                          \
        for (int j = 0; j < 4; ++j)                                                \
            *(unsigned*)&Bs[buf][c4 + j][2 * kp] = bfpack(bR0[j], bR1[j]);         \
    }

#define COMPUTE(buf)                                                               \
    {                                                                              \
        bf16x8 af[4], bfv[4];                                                      \
        _Pragma("unroll")                                                          \
        for (int m = 0; m < 4; ++m)                                                \
            af[m] = *(const bf16x8*)&As[buf][wr * 64 + m * 16 + l15][lg * 8];      \
        _Pragma("unroll")                                                          \
        for (int n = 0; n < 4; ++n)                                                \
            bfv[n] = *(const bf16x8*)&Bs[buf][wc * 64 + n * 16 + l15][lg * 8];     \
        _Pragma("unroll")                                                          \
        for (int m = 0; m < 4; ++m)                                                \
            _Pragma("unroll")                                                      \
            for (int n = 0; n < 4; ++n)                                            \
                acc[m][n] = __builtin_amdgcn_mfma_f32_16x16x32_bf16(af[m], bfv[n], acc[m][n], 0, 0, 0); \
    }

    LOADG(0);
    WRITELDS(0);
    __syncthreads();

    #pragma unroll 2
    for (int ks = 0; ks < KCH / 32; ++ks) {
        int cur = ks & 1;
        if (ks < KCH / 32 - 1) LOADG(ks + 1);
        COMPUTE(cur);
        if (ks < KCH / 32 - 1) WRITELDS(cur ^ 1);
        __syncthreads();
    }

    float* Pp = partial + (size_t)ch * CHUNK + (size_t)nt * 128;
    #pragma unroll
    for (int m = 0; m < 4; ++m)
        #pragma unroll
        for (int n = 0; n < 4; ++n)
            #pragma unroll
            for (int rr = 0; rr < 4; ++rr)
                Pp[(size_t)(wr * 64 + m * 16 + lg * 4 + rr) * 256 + wc * 64 + n * 16 + l15]
                    = acc[m][n][rr];

#undef LOADG
#undef WRITELDS
#undef COMPUTE
}

// ---------------------------------------------------------------------------
// K3: fused tail. Phase A: reduce partials + GRN + LN + softmax -> wts (LDS).
// Phase B: dense = xbf(64x128) @ WdTg^T(128x128) via MFMA, out = (dense+bd)*wts.
// grid 256 (batch), block 256.
// ---------------------------------------------------------------------------
__global__ __launch_bounds__(256) void k_tail(const float* __restrict__ partial,
                                              const unsigned short* __restrict__ xbf,
                                              const unsigned short* __restrict__ WdTg,
                                              const float* __restrict__ b2,
                                              const float* __restrict__ W1,
                                              const float* __restrict__ b1,
                                              const float* __restrict__ Wg,
                                              const float* __restrict__ bg,
                                              const float* __restrict__ Wv,
                                              const float* __restrict__ bv,
                                              const float* __restrict__ bs,
                                              const float* __restrict__ gamma,
                                              const float* __restrict__ beta,
                                              const float* __restrict__ bd,
                                              float* __restrict__ out) {
    int b = blockIdx.x, tid = threadIdx.x;
    __shared__ float hs[128], ss[128], h2s[128];
    __shared__ float gv[2][128], red2[2][128];
    __shared__ float ys[128], es[128], wts_s[128];

    // ---- phase A: GRN ----
    float rsum = 0.f;
    const float* Pp = partial + (size_t)b * 256 + tid;
    #pragma unroll 8
    for (int ch = 0; ch < NCH; ++ch) rsum += Pp[(size_t)ch * CHUNK];

    if (tid < 128) {
        float hp = rsum + b2[tid];
        hs[tid] = hp > 0.f ? hp : expm1f(hp);
    } else {
        ss[tid - 128] = rsum + bs[tid - 128];
    }
    __syncthreads();

    int c = tid & 127, half = tid >> 7;
    {
        float s = 0.f;
        int kb = half * 64;
        #pragma unroll 8
        for (int k = 0; k < 64; ++k) s += hs[kb + k] * W1[(size_t)(kb + k) * 128 + c];
        red2[half][c] = s;
    }
    __syncthreads();
    if (tid < 128) h2s[tid] = red2[0][tid] + red2[1][tid] + b1[tid];
    __syncthreads();
    {
        const float* Wx = half ? Wv : Wg;
        float s = 0.f;
        #pragma unroll 8
        for (int k = 0; k < 128; ++k) s += h2s[k] * Wx[(size_t)k * 128 + c];
        gv[half][c] = s;
    }
    __syncthreads();
    if (tid < 128) {
        float g = 1.f / (1.f + expf(-(gv[0][c] + bg[c])));
        float v = gv[1][c] + bv[c];
        ys[c] = ss[c] + g * v;
    }
    __syncthreads();

    float sum = 0.f, sq = 0.f;
    for (int k = 0; k < 128; ++k) { float v = ys[k]; sum += v; sq += v * v; }
    float mu = sum * (1.f / 128.f);
    float var = sq * (1.f / 128.f) - mu * mu;
    float rs = rsqrtf(var + LN_EPS);
    float yn = (ys[c] - mu) * rs * gamma[c] + beta[c];
    if (tid < 128) es[c] = yn;
    __syncthreads();
    float m = -1e30f;
    for (int k = 0; k < 128; ++k) m = fmaxf(m, es[k]);
    float e = expf(yn - m);
    __syncthreads();
    if (tid < 128) ys[c] = e;
    __syncthreads();
    float se = 0.f;
    for (int k = 0; k < 128; ++k) se += ys[k];
    if (tid < 128) wts_s[c] = e / se;
    __syncthreads();

    // ---- phase B: dense MFMA, frags straight from global (xbf, WdTg) ----
    int w4 = tid >> 6, lane = tid & 63;
    int l15 = lane & 15, lg = lane >> 4;
    const unsigned short* xrow = xbf + (size_t)b * 8192;

    f32x4 dacc[4][2];
    #pragma unroll
    for (int fm = 0; fm < 4; ++fm)
        #pragma unroll
        for (int fn = 0; fn < 2; ++fn) dacc[fm][fn] = (f32x4){0.f, 0.f, 0.f, 0.f};

    #pragma unroll
    for (int ks = 0; ks < 4; ++ks) {
        bf16x8 av[4], bv2[2];
        #pragma unroll
        for (int fm = 0; fm < 4; ++fm)
            av[fm] = *(const bf16x8*)(xrow + (size_t)(fm * 16 + l15) * 128 + ks * 32 + lg * 8);
        #pragma unroll
        for (int fn = 0; fn < 2; ++fn)
            bv2[fn] = *(const bf16x8*)(WdTg + (size_t)(w4 * 32 + fn * 16 + l15) * 128 + ks * 32 + lg * 8);
        #pragma unroll
        for (int fm = 0; fm < 4; ++fm)
            #pragma unroll
            for (int fn = 0; fn < 2; ++fn)
                dacc[fm][fn] = __builtin_amdgcn_mfma_f32_16x16x32_bf16(av[fm], bv2[fn], dacc[fm][fn], 0, 0, 0);
    }

    #pragma unroll
    for (int fm = 0; fm < 4; ++fm)
        #pragma unroll
        for (int fn = 0; fn < 2; ++fn)
            #pragma unroll
            for (int rr = 0; rr < 4; ++rr) {
                int t = fm * 16 + lg * 4 + rr;
                int dcol = w4 * 32 + fn * 16 + l15;
                out[(size_t)b * 8192 + (size_t)t * 128 + dcol]
                    = (dacc[fm][fn][rr] + bd[dcol]) * wts_s[dcol];
            }
}

// ---------------------------------------------------------------------------
extern "C" void kernel_launch(void* const* d_in, const int* in_sizes, int n_in,
                              void* d_out, int out_size, void* d_ws, size_t ws_size,
                              hipStream_t stream) {
    const float* inputs = (const float*)d_in[0];
    const float* tk     = (const float*)d_in[1];
    const float* Wd     = (const float*)d_in[2];
    const float* bd     = (const float*)d_in[3];
    const float* W2     = (const float*)d_in[4];
    const float* b2     = (const float*)d_in[5];
    const float* W1     = (const float*)d_in[6];
    const float* b1     = (const float*)d_in[7];
    const float* Wg     = (const float*)d_in[8];
    const float* bg     = (const float*)d_in[9];
    const float* Wv     = (const float*)d_in[10];
    const float* bv     = (const float*)d_in[11];
    const float* Ws     = (const float*)d_in[12];
    const float* bs     = (const float*)d_in[13];
    const float* gamma  = (const float*)d_in[14];
    const float* beta   = (const float*)d_in[15];
    float* out = (float*)d_out;

    char* ws = (char*)d_ws;
    unsigned short* sig  = (unsigned short*)ws;                        // 8,454,144 B
    float* partial       = (float*)(ws + 8454144);                     // 22,544,384 B
    unsigned short* xbf  = (unsigned short*)(ws + 30998528);           // 4,194,304 B
    unsigned short* WdTg = (unsigned short*)(ws + 35192832);           // 32,768 B

    k_sig <<<257, 256, 0, stream>>>(inputs, tk, Wd, sig, xbf, WdTg);
    k_gemm<<<NCH * 2, 512, 0, stream>>>(sig, W2, Ws, partial);
    k_tail<<<256, 256, 0, stream>>>(partial, xbf, WdTg, b2, W1, b1, Wg, bg, Wv, bv,
                                    bs, gamma, beta, bd, out);
}